// Round 2
// baseline (1352.641 us; speedup 1.0000x reference)
//
#include <hip/hip_runtime.h>
#include <hip/hip_bf16.h>

#define N_NODES 100000
#define N_EDGES 1600000
#define IN_DIM 128
#define HID_DIM 64
#define EMB_DIM 64
#define OUT_DIM 40

__device__ __forceinline__ float bf2f(unsigned short u) {
    unsigned int v = ((unsigned int)u) << 16;
    float f;
    __builtin_memcpy(&f, &v, 4);
    return f;
}

// flags[0]: 1 = float tensors are bf16, 0 = fp32
// flags[1]: 1 = edge_index is int64, 0 = int32
__device__ __forceinline__ float loadf(const void* p, size_t i, int isbf) {
    return isbf ? bf2f(((const unsigned short*)p)[i]) : ((const float*)p)[i];
}
__device__ __forceinline__ int loadi(const void* p, size_t i, int is64) {
    return is64 ? (int)(((const long long*)p)[i]) : ((const int*)p)[i];
}

// ---- dtype detection: 1 block x 64 threads ----
__global__ void k_detect(const unsigned int* __restrict__ xb,
                         const unsigned int* __restrict__ eib,
                         int* __restrict__ flags) {
    int tid = threadIdx.x;  // 64
    // float check: low ushort of word, viewed as bf16, has plausible N(0,1) exponent?
    unsigned int u = xb[tid];
    unsigned int lo_exp = (u >> 7) & 0xFF;
    bool bfplaus = (lo_exp >= 100 && lo_exp <= 140) || ((u & 0xFFFFu) == 0u);
    unsigned long long m1 = __ballot(bfplaus);
    // index check: odd int32 words all zero <=> int64 (high words of small indices)
    unsigned int hi = eib[2 * tid + 1];
    unsigned long long m2 = __ballot(hi == 0u);
    if (tid == 0) {
        flags[0] = (__popcll(m1) >= 48) ? 1 : 0;
        flags[1] = (m2 == 0xFFFFFFFFFFFFFFFFULL) ? 1 : 0;
    }
}

// deg[i] = 1.0 (self loop)
__global__ void k_deg_init(float* __restrict__ deg, int n) {
    int i = blockIdx.x * blockDim.x + threadIdx.x;
    if (i < n) deg[i] = 1.0f;
}

// deg[dst[e]] += 1
__global__ void k_deg_count(const void* __restrict__ ei, float* __restrict__ deg,
                            const int* __restrict__ flags, int E) {
    int is64 = flags[1];
    int i = blockIdx.x * blockDim.x + threadIdx.x;
    int stride = gridDim.x * blockDim.x;
    for (int e = i; e < E; e += stride) {
        int d = loadi(ei, (size_t)N_EDGES + e, is64);
        unsafeAtomicAdd(&deg[d], 1.0f);
    }
}

// in-place deg -> rsqrt(deg)
__global__ void k_dinv(float* __restrict__ deg, int n) {
    int i = blockIdx.x * blockDim.x + threadIdx.x;
    if (i < n) deg[i] = rsqrtf(deg[i]);
}

// out[r][j] = sum_k x[r][k] * W1[k][j] ; one wave per row, lane j = out col
__global__ __launch_bounds__(256) void k_gemm1(const void* __restrict__ x,
                                               const void* __restrict__ W1,
                                               float* __restrict__ out,
                                               const int* __restrict__ flags, int n) {
    __shared__ float Ws[IN_DIM * HID_DIM];  // 32 KB
    int isbf = flags[0];
    int tid = threadIdx.x;
    for (int i = tid; i < IN_DIM * HID_DIM; i += 256) Ws[i] = loadf(W1, i, isbf);
    __syncthreads();
    int lane = tid & 63, wv = tid >> 6;
    int r = blockIdx.x * 4 + wv;
    if (r >= n) return;
    float xa, xb;
    if (isbf) {
        ushort2 p = ((const ushort2*)((const unsigned short*)x + (size_t)r * IN_DIM))[lane];
        xa = bf2f(p.x); xb = bf2f(p.y);
    } else {
        float2 p = ((const float2*)((const float*)x + (size_t)r * IN_DIM))[lane];
        xa = p.x; xb = p.y;
    }
    float acc = 0.0f;
#pragma unroll
    for (int k2 = 0; k2 < 64; ++k2) {
        acc = fmaf(__shfl(xa, k2), Ws[(2 * k2) * HID_DIM + lane], acc);
        acc = fmaf(__shfl(xb, k2), Ws[(2 * k2 + 1) * HID_DIM + lane], acc);
    }
    out[(size_t)r * HID_DIM + lane] = acc;
}

// agg[i][j] = h[i][j] * dinv[i]^2  (self-loop message; initializes agg)
__global__ void k_agg_init(const float* __restrict__ h, const float* __restrict__ dinv,
                           float* __restrict__ agg, int n) {
    int i = blockIdx.x * blockDim.x + threadIdx.x;
    if (i < n * 64) {
        int node = i >> 6;
        float d = dinv[node];
        agg[i] = h[i] * d * d;
    }
}

// agg[dst][j] += h[src][j] * dinv[src]*dinv[dst] ; one wave per edge, grid-stride
__global__ __launch_bounds__(256) void k_scatter(const float* __restrict__ h,
                                                 const float* __restrict__ dinv,
                                                 const void* __restrict__ ei,
                                                 float* __restrict__ agg,
                                                 const int* __restrict__ flags, int E) {
    int is64 = flags[1];
    int lane = threadIdx.x & 63;
    int wave = blockIdx.x * 4 + (threadIdx.x >> 6);
    int nwaves = gridDim.x * 4;
    for (int e = wave; e < E; e += nwaves) {
        int s = loadi(ei, e, is64);
        int d = loadi(ei, (size_t)N_EDGES + e, is64);
        float w = dinv[s] * dinv[d];
        float v = h[(size_t)s * 64 + lane] * w;
        unsafeAtomicAdd(&agg[(size_t)d * 64 + lane], v);
    }
}

// out[r][j] = sum_k relu(in[r][k] + b1[k]) * W2[k][j]
__global__ __launch_bounds__(256) void k_gemm2(const float* __restrict__ in,
                                               const void* __restrict__ W2,
                                               const void* __restrict__ b1,
                                               float* __restrict__ out,
                                               const int* __restrict__ flags, int n) {
    __shared__ float Ws[HID_DIM * EMB_DIM];  // 16 KB
    __shared__ float bs[HID_DIM];
    int isbf = flags[0];
    int tid = threadIdx.x;
    for (int i = tid; i < HID_DIM * EMB_DIM; i += 256) Ws[i] = loadf(W2, i, isbf);
    if (tid < HID_DIM) bs[tid] = loadf(b1, tid, isbf);
    __syncthreads();
    int lane = tid & 63, wv = tid >> 6;
    int r = blockIdx.x * 4 + wv;
    if (r >= n) return;
    float a = in[(size_t)r * HID_DIM + lane] + bs[lane];
    a = fmaxf(a, 0.0f);
    float acc = 0.0f;
#pragma unroll
    for (int k = 0; k < 64; ++k) {
        acc = fmaf(__shfl(a, k), Ws[k * EMB_DIM + lane], acc);
    }
    out[(size_t)r * EMB_DIM + lane] = acc;
}

// per node: emb = agg2 + b2 ; logits = emb @ Wl + bl ; log_softmax ; store
__global__ __launch_bounds__(256) void k_final(const float* __restrict__ agg2,
                                               const void* __restrict__ b2,
                                               const void* __restrict__ Wl,
                                               const void* __restrict__ bl,
                                               void* __restrict__ out,
                                               const int* __restrict__ flags, int n) {
    __shared__ float Ws[EMB_DIM * OUT_DIM + 64];  // padded tail zero-inited
    __shared__ float b2s[EMB_DIM];
    __shared__ float bls[OUT_DIM];
    int isbf = flags[0];
    int tid = threadIdx.x;
    for (int i = tid; i < EMB_DIM * OUT_DIM + 64; i += 256)
        Ws[i] = (i < EMB_DIM * OUT_DIM) ? loadf(Wl, i, isbf) : 0.0f;
    if (tid < EMB_DIM) b2s[tid] = loadf(b2, tid, isbf);
    if (tid >= 64 && tid < 64 + OUT_DIM) bls[tid - 64] = loadf(bl, tid - 64, isbf);
    __syncthreads();
    int lane = tid & 63, wv = tid >> 6;
    int r = blockIdx.x * 4 + wv;
    if (r >= n) return;
    float e = agg2[(size_t)r * EMB_DIM + lane] + b2s[lane];
    float acc = (lane < OUT_DIM) ? bls[lane] : 0.0f;
#pragma unroll
    for (int k = 0; k < 64; ++k) {
        acc = fmaf(__shfl(e, k), Ws[k * OUT_DIM + lane], acc);
    }
    float lv = (lane < OUT_DIM) ? acc : -INFINITY;
#pragma unroll
    for (int off = 32; off; off >>= 1) lv = fmaxf(lv, __shfl_xor(lv, off));
    float ex = (lane < OUT_DIM) ? expf(acc - lv) : 0.0f;
    float ssum = ex;
#pragma unroll
    for (int off = 32; off; off >>= 1) ssum += __shfl_xor(ssum, off);
    if (lane < OUT_DIM) {
        float v = acc - lv - logf(ssum);
        size_t o = (size_t)r * OUT_DIM + lane;
        if (isbf) ((__hip_bfloat16*)out)[o] = __float2bfloat16(v);
        else ((float*)out)[o] = v;
    }
}

extern "C" void kernel_launch(void* const* d_in, const int* in_sizes, int n_in,
                              void* d_out, int out_size, void* d_ws, size_t ws_size,
                              hipStream_t stream) {
    const void* x  = d_in[0];
    const void* ei = d_in[1];
    const void* W1 = d_in[2];
    const void* b1 = d_in[3];
    const void* W2 = d_in[4];
    const void* b2 = d_in[5];
    const void* Wl = d_in[6];
    const void* bl = d_in[7];

    float* ws = (float*)d_ws;
    int* flags  = (int*)ws;                        // 2 ints (64-float slot)
    float* dinv = ws + 64;                         // N floats (deg -> dinv in place)
    float* bufA = ws + 100096;                     // N*64 floats
    float* bufB = bufA + (size_t)N_NODES * 64;     // N*64 floats

    const int nblk_node = (N_NODES + 255) / 256;   // 391
    const int nblk_feat = (N_NODES * 64) / 256;    // 25000
    const int nblk_row  = N_NODES / 4;             // 25000

    k_detect<<<1, 64, 0, stream>>>((const unsigned int*)x, (const unsigned int*)ei, flags);

    // degree (with self loop) -> dinv
    k_deg_init<<<nblk_node, 256, 0, stream>>>(dinv, N_NODES);
    k_deg_count<<<2048, 256, 0, stream>>>(ei, dinv, flags, N_EDGES);
    k_dinv<<<nblk_node, 256, 0, stream>>>(dinv, N_NODES);

    // layer 1
    k_gemm1<<<nblk_row, 256, 0, stream>>>(x, W1, bufA, flags, N_NODES);
    k_agg_init<<<nblk_feat, 256, 0, stream>>>(bufA, dinv, bufB, N_NODES);
    k_scatter<<<8192, 256, 0, stream>>>(bufA, dinv, ei, bufB, flags, N_EDGES);

    // layer 2
    k_gemm2<<<nblk_row, 256, 0, stream>>>(bufB, W2, b1, bufA, flags, N_NODES);
    k_agg_init<<<nblk_feat, 256, 0, stream>>>(bufA, dinv, bufB, N_NODES);
    k_scatter<<<8192, 256, 0, stream>>>(bufA, dinv, ei, bufB, flags, N_EDGES);

    // head
    k_final<<<nblk_row, 256, 0, stream>>>(bufB, b2, Wl, bl, d_out, flags, N_NODES);
}

// Round 3
// 902.877 us; speedup vs baseline: 1.4981x; 1.4981x over previous
//
#include <hip/hip_runtime.h>
#include <hip/hip_bf16.h>

#define N_NODES 100000
#define N_EDGES 1600000
#define IN_DIM 128
#define HID_DIM 64
#define EMB_DIM 64
#define OUT_DIM 40

__device__ __forceinline__ float bf2f(unsigned short u) {
    unsigned int v = ((unsigned int)u) << 16;
    float f;
    __builtin_memcpy(&f, &v, 4);
    return f;
}
__device__ __forceinline__ unsigned short f2bf(float f) {
    __hip_bfloat16 b = __float2bfloat16(f);
    unsigned short u;
    __builtin_memcpy(&u, &b, 2);
    return u;
}

// flags[0]: 1 = float tensors are bf16, 0 = fp32
// flags[1]: 1 = edge_index is int64, 0 = int32
__device__ __forceinline__ float loadf(const void* p, size_t i, int isbf) {
    return isbf ? bf2f(((const unsigned short*)p)[i]) : ((const float*)p)[i];
}
__device__ __forceinline__ int loadi(const void* p, size_t i, int is64) {
    return is64 ? (int)(((const long long*)p)[i]) : ((const int*)p)[i];
}

// ---- dtype detection: 1 block x 64 threads ----
__global__ void k_detect(const unsigned int* __restrict__ xb,
                         const unsigned int* __restrict__ eib,
                         int* __restrict__ flags) {
    int tid = threadIdx.x;
    unsigned int u = xb[tid];
    unsigned int lo_exp = (u >> 7) & 0xFF;
    bool bfplaus = (lo_exp >= 100 && lo_exp <= 140) || ((u & 0xFFFFu) == 0u);
    unsigned long long m1 = __ballot(bfplaus);
    unsigned int hi = eib[2 * tid + 1];
    unsigned long long m2 = __ballot(hi == 0u);
    if (tid == 0) {
        flags[0] = (__popcll(m1) >= 48) ? 1 : 0;
        flags[1] = (m2 == 0xFFFFFFFFFFFFFFFFULL) ? 1 : 0;
    }
}

__global__ void k_zero(int* __restrict__ cnt, int n) {
    int i = blockIdx.x * blockDim.x + threadIdx.x;
    if (i < n) cnt[i] = 0;
}

// cnt[dst[e]] += 1  (int atomics)
__global__ void k_count(const void* __restrict__ ei, int* __restrict__ cnt,
                        const int* __restrict__ flags, int E) {
    int is64 = flags[1];
    int i = blockIdx.x * blockDim.x + threadIdx.x;
    int stride = gridDim.x * blockDim.x;
    for (int e = i; e < E; e += stride) {
        int d = loadi(ei, (size_t)N_EDGES + e, is64);
        atomicAdd(&cnt[d], 1);
    }
}

// dinv[i] = rsqrt(1 + cnt[i])   (self loop included)
__global__ void k_dinv(const int* __restrict__ cnt, float* __restrict__ dinv, int n) {
    int i = blockIdx.x * blockDim.x + threadIdx.x;
    if (i < n) dinv[i] = rsqrtf(1.0f + (float)cnt[i]);
}

// ---- hierarchical exclusive scan: cnt[N] -> cur[N] (row start offsets) ----
// pass a: per-block (1024 elems) totals
__global__ __launch_bounds__(256) void k_scan_a(const int* __restrict__ cnt,
                                                int* __restrict__ blocksums, int n) {
    __shared__ int sh[256];
    int t = threadIdx.x, b = blockIdx.x;
    int base = (b * 256 + t) * 4;
    int s = 0;
#pragma unroll
    for (int j = 0; j < 4; ++j) if (base + j < n) s += cnt[base + j];
    sh[t] = s;
    __syncthreads();
    for (int o = 1; o < 256; o <<= 1) {
        int u = (t >= o) ? sh[t - o] : 0;
        __syncthreads();
        sh[t] += u;
        __syncthreads();
    }
    if (t == 255) blocksums[b] = sh[255];
}

// pass b: scan block sums (nb <= 128) -> exclusive offsets
__global__ void k_scan_b(int* __restrict__ blocksums, int nb) {
    __shared__ int sh[128];
    int t = threadIdx.x;
    int v = (t < nb) ? blocksums[t] : 0;
    sh[t] = v;
    __syncthreads();
    for (int o = 1; o < 128; o <<= 1) {
        int u = (t >= o) ? sh[t - o] : 0;
        __syncthreads();
        sh[t] += u;
        __syncthreads();
    }
    if (t < nb) blocksums[t] = sh[t] - v;  // exclusive
}

// pass c: recompute local scan, add block offset, write cur
__global__ __launch_bounds__(256) void k_scan_c(const int* __restrict__ cnt,
                                                const int* __restrict__ blocksums,
                                                int* __restrict__ cur, int n) {
    __shared__ int sh[256];
    int t = threadIdx.x, b = blockIdx.x;
    int base = (b * 256 + t) * 4;
    int c[4];
    int s = 0;
#pragma unroll
    for (int j = 0; j < 4; ++j) {
        c[j] = (base + j < n) ? cnt[base + j] : 0;
        s += c[j];
    }
    sh[t] = s;
    __syncthreads();
    for (int o = 1; o < 256; o <<= 1) {
        int u = (t >= o) ? sh[t - o] : 0;
        __syncthreads();
        sh[t] += u;
        __syncthreads();
    }
    int off = blocksums[b] + sh[t] - s;  // exclusive thread base
#pragma unroll
    for (int j = 0; j < 4; ++j) {
        if (base + j < n) cur[base + j] = off;
        off += c[j];
    }
}

// fill CSR: pos = cur[dst]++ ; csr_src[pos] = src
// after this kernel, cur[d] = end offset of row d (start = cur[d-1], or 0)
__global__ void k_fill(const void* __restrict__ ei, int* __restrict__ cur,
                       int* __restrict__ csr_src, const int* __restrict__ flags, int E) {
    int is64 = flags[1];
    int i = blockIdx.x * blockDim.x + threadIdx.x;
    int stride = gridDim.x * blockDim.x;
    for (int e = i; e < E; e += stride) {
        int s = loadi(ei, e, is64);
        int d = loadi(ei, (size_t)N_EDGES + e, is64);
        int pos = atomicAdd(&cur[d], 1);
        csr_src[pos] = s;
    }
}

// out[r][j] = sum_k x[r][k] * W1[k][j] ; one wave per row ; bf16 output
__global__ __launch_bounds__(256) void k_gemm1(const void* __restrict__ x,
                                               const void* __restrict__ W1,
                                               unsigned short* __restrict__ out,
                                               const int* __restrict__ flags, int n) {
    __shared__ float Ws[IN_DIM * HID_DIM];  // 32 KB
    int isbf = flags[0];
    int tid = threadIdx.x;
    for (int i = tid; i < IN_DIM * HID_DIM; i += 256) Ws[i] = loadf(W1, i, isbf);
    __syncthreads();
    int lane = tid & 63, wv = tid >> 6;
    int r = blockIdx.x * 4 + wv;
    if (r >= n) return;
    float xa, xb;
    if (isbf) {
        ushort2 p = ((const ushort2*)((const unsigned short*)x + (size_t)r * IN_DIM))[lane];
        xa = bf2f(p.x); xb = bf2f(p.y);
    } else {
        float2 p = ((const float2*)((const float*)x + (size_t)r * IN_DIM))[lane];
        xa = p.x; xb = p.y;
    }
    float acc = 0.0f;
#pragma unroll
    for (int k2 = 0; k2 < 64; ++k2) {
        acc = fmaf(__shfl(xa, k2), Ws[(2 * k2) * HID_DIM + lane], acc);
        acc = fmaf(__shfl(xb, k2), Ws[(2 * k2 + 1) * HID_DIM + lane], acc);
    }
    out[(size_t)r * HID_DIM + lane] = f2bf(acc);
}

// gather aggregation: out[d] = dinv[d] * ( h[d]*dinv[d] + sum_{s in row d} h[s]*dinv[s] )
// one wave per node; half-wave per edge (2 edges/iter), lane loads ushort2 (4B)
__global__ __launch_bounds__(256) void k_aggregate(const unsigned short* __restrict__ h,
                                                   const float* __restrict__ dinv,
                                                   const int* __restrict__ cur,
                                                   const int* __restrict__ csr_src,
                                                   float* __restrict__ out, int n) {
    int lane = threadIdx.x & 63;
    int half = lane >> 5;
    int col2 = lane & 31;
    int node = blockIdx.x * 4 + (threadIdx.x >> 6);
    if (node >= n) return;
    int start = (node == 0) ? 0 : cur[node - 1];
    int end = cur[node];
    float ax = 0.0f, ay = 0.0f;
    const ushort2* h2 = (const ushort2*)h;
    for (int e = start + half; e < end; e += 2) {
        int s = csr_src[e];
        ushort2 p = h2[(size_t)s * 32 + col2];
        float w = dinv[s];
        ax = fmaf(bf2f(p.x), w, ax);
        ay = fmaf(bf2f(p.y), w, ay);
    }
    ax += __shfl_xor(ax, 32);
    ay += __shfl_xor(ay, 32);
    if (half == 0) {
        float dd = dinv[node];
        ushort2 ps = h2[(size_t)node * 32 + col2];
        float2 r;
        r.x = (ax + bf2f(ps.x) * dd) * dd;
        r.y = (ay + bf2f(ps.y) * dd) * dd;
        ((float2*)out)[(size_t)node * 32 + col2] = r;
    }
}

// out[r][j] = sum_k relu(in[r][k] + b1[k]) * W2[k][j] ; bf16 output
__global__ __launch_bounds__(256) void k_gemm2(const float* __restrict__ in,
                                               const void* __restrict__ W2,
                                               const void* __restrict__ b1,
                                               unsigned short* __restrict__ out,
                                               const int* __restrict__ flags, int n) {
    __shared__ float Ws[HID_DIM * EMB_DIM];  // 16 KB
    __shared__ float bs[HID_DIM];
    int isbf = flags[0];
    int tid = threadIdx.x;
    for (int i = tid; i < HID_DIM * EMB_DIM; i += 256) Ws[i] = loadf(W2, i, isbf);
    if (tid < HID_DIM) bs[tid] = loadf(b1, tid, isbf);
    __syncthreads();
    int lane = tid & 63, wv = tid >> 6;
    int r = blockIdx.x * 4 + wv;
    if (r >= n) return;
    float a = in[(size_t)r * HID_DIM + lane] + bs[lane];
    a = fmaxf(a, 0.0f);
    float acc = 0.0f;
#pragma unroll
    for (int k = 0; k < 64; ++k) {
        acc = fmaf(__shfl(a, k), Ws[k * EMB_DIM + lane], acc);
    }
    out[(size_t)r * EMB_DIM + lane] = f2bf(acc);
}

// per node: emb = agg2 + b2 ; logits = emb @ Wl + bl ; log_softmax ; store
__global__ __launch_bounds__(256) void k_final(const float* __restrict__ agg2,
                                               const void* __restrict__ b2,
                                               const void* __restrict__ Wl,
                                               const void* __restrict__ bl,
                                               void* __restrict__ out,
                                               const int* __restrict__ flags, int n) {
    __shared__ float Ws[EMB_DIM * OUT_DIM + 64];
    __shared__ float b2s[EMB_DIM];
    __shared__ float bls[OUT_DIM];
    int isbf = flags[0];
    int tid = threadIdx.x;
    for (int i = tid; i < EMB_DIM * OUT_DIM + 64; i += 256)
        Ws[i] = (i < EMB_DIM * OUT_DIM) ? loadf(Wl, i, isbf) : 0.0f;
    if (tid < EMB_DIM) b2s[tid] = loadf(b2, tid, isbf);
    if (tid >= 64 && tid < 64 + OUT_DIM) bls[tid - 64] = loadf(bl, tid - 64, isbf);
    __syncthreads();
    int lane = tid & 63, wv = tid >> 6;
    int r = blockIdx.x * 4 + wv;
    if (r >= n) return;
    float e = agg2[(size_t)r * EMB_DIM + lane] + b2s[lane];
    float acc = (lane < OUT_DIM) ? bls[lane] : 0.0f;
#pragma unroll
    for (int k = 0; k < 64; ++k) {
        acc = fmaf(__shfl(e, k), Ws[k * OUT_DIM + lane], acc);
    }
    float lv = (lane < OUT_DIM) ? acc : -INFINITY;
#pragma unroll
    for (int off = 32; off; off >>= 1) lv = fmaxf(lv, __shfl_xor(lv, off));
    float ex = (lane < OUT_DIM) ? expf(acc - lv) : 0.0f;
    float ssum = ex;
#pragma unroll
    for (int off = 32; off; off >>= 1) ssum += __shfl_xor(ssum, off);
    if (lane < OUT_DIM) {
        float v = acc - lv - logf(ssum);
        size_t o = (size_t)r * OUT_DIM + lane;
        if (isbf) ((__hip_bfloat16*)out)[o] = __float2bfloat16(v);
        else ((float*)out)[o] = v;
    }
}

extern "C" void kernel_launch(void* const* d_in, const int* in_sizes, int n_in,
                              void* d_out, int out_size, void* d_ws, size_t ws_size,
                              hipStream_t stream) {
    const void* x  = d_in[0];
    const void* ei = d_in[1];
    const void* W1 = d_in[2];
    const void* b1 = d_in[3];
    const void* W2 = d_in[4];
    const void* b2 = d_in[5];
    const void* Wl = d_in[6];
    const void* bl = d_in[7];

    float* ws = (float*)d_ws;
    // layout (float-index offsets):
    int*   flags     = (int*)ws;                           // [0..63]
    float* dinv      = ws + 64;                            // N floats
    int*   cnt       = (int*)(ws + 100096);                // N ints
    int*   cur       = (int*)(ws + 200128);                // N ints
    int*   blocksums = (int*)(ws + 300160);                // 128 ints
    int*   csr_src   = (int*)(ws + 300416);                // E ints
    unsigned short* bufA = (unsigned short*)(ws + 1900544);// N*64 bf16 (3.2M floats)
    float* bufB      = ws + 5100544;                       // N*64 floats
    // total: 11,500,544 floats = 46.0 MB

    const int nblk_node = (N_NODES + 255) / 256;   // 391
    const int nblk_row  = N_NODES / 4;             // 25000
    const int nblk_scan = (N_NODES + 1023) / 1024; // 98

    k_detect<<<1, 64, 0, stream>>>((const unsigned int*)x, (const unsigned int*)ei, flags);

    // CSR build + dinv
    k_zero<<<nblk_node, 256, 0, stream>>>(cnt, N_NODES);
    k_count<<<2048, 256, 0, stream>>>(ei, cnt, flags, N_EDGES);
    k_dinv<<<nblk_node, 256, 0, stream>>>(cnt, dinv, N_NODES);
    k_scan_a<<<nblk_scan, 256, 0, stream>>>(cnt, blocksums, N_NODES);
    k_scan_b<<<1, 128, 0, stream>>>(blocksums, nblk_scan);
    k_scan_c<<<nblk_scan, 256, 0, stream>>>(cnt, blocksums, cur, N_NODES);
    k_fill<<<2048, 256, 0, stream>>>(ei, cur, csr_src, flags, N_EDGES);

    // layer 1
    k_gemm1<<<nblk_row, 256, 0, stream>>>(x, W1, bufA, flags, N_NODES);
    k_aggregate<<<nblk_row, 256, 0, stream>>>(bufA, dinv, cur, csr_src, bufB, N_NODES);

    // layer 2
    k_gemm2<<<nblk_row, 256, 0, stream>>>(bufB, W2, b1, bufA, flags, N_NODES);
    k_aggregate<<<nblk_row, 256, 0, stream>>>(bufA, dinv, cur, csr_src, bufB, N_NODES);

    // head
    k_final<<<nblk_row, 256, 0, stream>>>(bufB, b2, Wl, bl, d_out, flags, N_NODES);
}

// Round 4
// 532.738 us; speedup vs baseline: 2.5390x; 1.6948x over previous
//
#include <hip/hip_runtime.h>
#include <hip/hip_bf16.h>

#define N_NODES 100000
#define N_EDGES 1600000
#define IN_DIM 128
#define HID_DIM 64
#define EMB_DIM 64
#define OUT_DIM 40
#define NTILES 6250  // N_NODES / 16

typedef __attribute__((ext_vector_type(8))) short bf16x8;
typedef __attribute__((ext_vector_type(4))) float f32x4;

__device__ __forceinline__ float bf2f(unsigned short u) {
    unsigned int v = ((unsigned int)u) << 16;
    float f;
    __builtin_memcpy(&f, &v, 4);
    return f;
}
__device__ __forceinline__ unsigned short f2bf(float f) {
    __hip_bfloat16 b = __float2bfloat16(f);
    unsigned short u;
    __builtin_memcpy(&u, &b, 2);
    return u;
}

// flags[0]: 1 = float tensors are bf16, 0 = fp32
// flags[1]: 1 = edge_index is int64, 0 = int32
__device__ __forceinline__ float loadf(const void* p, size_t i, int isbf) {
    return isbf ? bf2f(((const unsigned short*)p)[i]) : ((const float*)p)[i];
}
__device__ __forceinline__ int loadi(const void* p, size_t i, int is64) {
    return is64 ? (int)(((const long long*)p)[i]) : ((const int*)p)[i];
}

// ---- dtype detection: 1 block x 64 threads ----
__global__ void k_detect(const unsigned int* __restrict__ xb,
                         const unsigned int* __restrict__ eib,
                         int* __restrict__ flags) {
    int tid = threadIdx.x;
    unsigned int u = xb[tid];
    unsigned int lo_exp = (u >> 7) & 0xFF;
    bool bfplaus = (lo_exp >= 100 && lo_exp <= 140) || ((u & 0xFFFFu) == 0u);
    unsigned long long m1 = __ballot(bfplaus);
    unsigned int hi = eib[2 * tid + 1];
    unsigned long long m2 = __ballot(hi == 0u);
    if (tid == 0) {
        flags[0] = (__popcll(m1) >= 48) ? 1 : 0;
        flags[1] = (m2 == 0xFFFFFFFFFFFFFFFFULL) ? 1 : 0;
    }
}

__global__ void k_zero(int* __restrict__ cnt, int n) {
    int i = blockIdx.x * blockDim.x + threadIdx.x;
    if (i < n) cnt[i] = 0;
}

__global__ void k_count(const void* __restrict__ ei, int* __restrict__ cnt,
                        const int* __restrict__ flags, int E) {
    int is64 = flags[1];
    int i = blockIdx.x * blockDim.x + threadIdx.x;
    int stride = gridDim.x * blockDim.x;
    for (int e = i; e < E; e += stride) {
        int d = loadi(ei, (size_t)N_EDGES + e, is64);
        atomicAdd(&cnt[d], 1);
    }
}

__global__ void k_dinv(const int* __restrict__ cnt, float* __restrict__ dinv, int n) {
    int i = blockIdx.x * blockDim.x + threadIdx.x;
    if (i < n) dinv[i] = rsqrtf(1.0f + (float)cnt[i]);
}

// ---- hierarchical exclusive scan ----
__global__ __launch_bounds__(256) void k_scan_a(const int* __restrict__ cnt,
                                                int* __restrict__ blocksums, int n) {
    __shared__ int sh[256];
    int t = threadIdx.x, b = blockIdx.x;
    int base = (b * 256 + t) * 4;
    int s = 0;
#pragma unroll
    for (int j = 0; j < 4; ++j) if (base + j < n) s += cnt[base + j];
    sh[t] = s;
    __syncthreads();
    for (int o = 1; o < 256; o <<= 1) {
        int u = (t >= o) ? sh[t - o] : 0;
        __syncthreads();
        sh[t] += u;
        __syncthreads();
    }
    if (t == 255) blocksums[b] = sh[255];
}

__global__ void k_scan_b(int* __restrict__ blocksums, int nb) {
    __shared__ int sh[128];
    int t = threadIdx.x;
    int v = (t < nb) ? blocksums[t] : 0;
    sh[t] = v;
    __syncthreads();
    for (int o = 1; o < 128; o <<= 1) {
        int u = (t >= o) ? sh[t - o] : 0;
        __syncthreads();
        sh[t] += u;
        __syncthreads();
    }
    if (t < nb) blocksums[t] = sh[t] - v;
}

__global__ __launch_bounds__(256) void k_scan_c(const int* __restrict__ cnt,
                                                const int* __restrict__ blocksums,
                                                int* __restrict__ cur, int n) {
    __shared__ int sh[256];
    int t = threadIdx.x, b = blockIdx.x;
    int base = (b * 256 + t) * 4;
    int c[4];
    int s = 0;
#pragma unroll
    for (int j = 0; j < 4; ++j) {
        c[j] = (base + j < n) ? cnt[base + j] : 0;
        s += c[j];
    }
    sh[t] = s;
    __syncthreads();
    for (int o = 1; o < 256; o <<= 1) {
        int u = (t >= o) ? sh[t - o] : 0;
        __syncthreads();
        sh[t] += u;
        __syncthreads();
    }
    int off = blocksums[b] + sh[t] - s;
#pragma unroll
    for (int j = 0; j < 4; ++j) {
        if (base + j < n) cur[base + j] = off;
        off += c[j];
    }
}

__global__ void k_fill(const void* __restrict__ ei, int* __restrict__ cur,
                       int* __restrict__ csr_src, const int* __restrict__ flags, int E) {
    int is64 = flags[1];
    int i = blockIdx.x * blockDim.x + threadIdx.x;
    int stride = gridDim.x * blockDim.x;
    for (int e = i; e < E; e += stride) {
        int s = loadi(ei, e, is64);
        int d = loadi(ei, (size_t)N_EDGES + e, is64);
        int pos = atomicAdd(&cur[d], 1);
        csr_src[pos] = s;
    }
}

// ---- MFMA GEMM1: out[N,64] = bf16( x[N,128] @ W1[128,64] ) ----
// wave computes 16x64 tile; A-frag direct from global; B-frags from LDS-transposed W1.
__global__ __launch_bounds__(256) void k_gemm1(const void* __restrict__ x,
                                               const void* __restrict__ W1,
                                               unsigned short* __restrict__ out,
                                               const int* __restrict__ flags, int n) {
    __shared__ unsigned short W1T[64 * 136];  // W1T[n][k], pitch 136 (16B-aligned rows, 2-way banks)
    int isbf = flags[0];
    int tid = threadIdx.x;
    for (int i = tid; i < IN_DIM * HID_DIM; i += 256) {
        int k = i >> 6, nn = i & 63;
        W1T[nn * 136 + k] = isbf ? ((const unsigned short*)W1)[i] : f2bf(((const float*)W1)[i]);
    }
    __syncthreads();
    int lane = tid & 63;
    int lane16 = lane & 15, quad = lane >> 4;
    bf16x8 bfrag[4][4];  // [col-tile][k-chunk]
#pragma unroll
    for (int ct = 0; ct < 4; ++ct)
#pragma unroll
        for (int kc = 0; kc < 4; ++kc)
            bfrag[ct][kc] = *(const bf16x8*)&W1T[(ct * 16 + lane16) * 136 + kc * 32 + quad * 8];
    int wid = (blockIdx.x * 256 + tid) >> 6;
    int nw = (gridDim.x * 256) >> 6;
    for (int t = wid; t < NTILES; t += nw) {
        int row0 = t * 16;
        bf16x8 afrag[4];
        if (isbf) {
            const unsigned short* xr = (const unsigned short*)x + (size_t)(row0 + lane16) * IN_DIM;
#pragma unroll
            for (int kc = 0; kc < 4; ++kc)
                afrag[kc] = *(const bf16x8*)(xr + kc * 32 + quad * 8);
        } else {
            const float* xr = (const float*)x + (size_t)(row0 + lane16) * IN_DIM;
#pragma unroll
            for (int kc = 0; kc < 4; ++kc) {
                f32x4 p0 = *(const f32x4*)(xr + kc * 32 + quad * 8);
                f32x4 p1 = *(const f32x4*)(xr + kc * 32 + quad * 8 + 4);
                bf16x8 a;
#pragma unroll
                for (int j = 0; j < 4; ++j) {
                    a[j] = (short)f2bf(p0[j]);
                    a[4 + j] = (short)f2bf(p1[j]);
                }
                afrag[kc] = a;
            }
        }
        f32x4 acc[4] = {};
#pragma unroll
        for (int kc = 0; kc < 4; ++kc)
#pragma unroll
            for (int ct = 0; ct < 4; ++ct)
                acc[ct] = __builtin_amdgcn_mfma_f32_16x16x32_bf16(afrag[kc], bfrag[ct][kc], acc[ct], 0, 0, 0);
#pragma unroll
        for (int ct = 0; ct < 4; ++ct)
#pragma unroll
            for (int r = 0; r < 4; ++r)
                out[(size_t)(row0 + quad * 4 + r) * HID_DIM + ct * 16 + lane16] = f2bf(acc[ct][r]);
    }
}

// gather aggregation: out[d] = dinv[d]*( h[d]*dinv[d] + sum_{s in row d} h[s]*dinv[s] )
__global__ __launch_bounds__(256) void k_aggregate(const unsigned short* __restrict__ h,
                                                   const float* __restrict__ dinv,
                                                   const int* __restrict__ cur,
                                                   const int* __restrict__ csr_src,
                                                   float* __restrict__ out, int n) {
    int lane = threadIdx.x & 63;
    int half = lane >> 5;
    int col2 = lane & 31;
    int node = blockIdx.x * 4 + (threadIdx.x >> 6);
    if (node >= n) return;
    int start = (node == 0) ? 0 : cur[node - 1];
    int end = cur[node];
    float ax = 0.0f, ay = 0.0f;
    const ushort2* h2 = (const ushort2*)h;
    for (int e = start + half; e < end; e += 2) {
        int s = csr_src[e];
        ushort2 p = h2[(size_t)s * 32 + col2];
        float w = dinv[s];
        ax = fmaf(bf2f(p.x), w, ax);
        ay = fmaf(bf2f(p.y), w, ay);
    }
    ax += __shfl_xor(ax, 32);
    ay += __shfl_xor(ay, 32);
    if (half == 0) {
        float dd = dinv[node];
        ushort2 ps = h2[(size_t)node * 32 + col2];
        float2 r;
        r.x = (ax + bf2f(ps.x) * dd) * dd;
        r.y = (ay + bf2f(ps.y) * dd) * dd;
        ((float2*)out)[(size_t)node * 32 + col2] = r;
    }
}

// ---- MFMA GEMM2: out[N,64] = bf16( relu(in[N,64]+b1) @ W2[64,64] ) ----
__global__ __launch_bounds__(256) void k_gemm2(const float* __restrict__ in,
                                               const void* __restrict__ W2,
                                               const void* __restrict__ b1,
                                               unsigned short* __restrict__ out,
                                               const int* __restrict__ flags, int n) {
    __shared__ unsigned short W2T[64 * 72];  // W2T[n][k], pitch 72
    __shared__ float bs[64];
    int isbf = flags[0];
    int tid = threadIdx.x;
    for (int i = tid; i < HID_DIM * EMB_DIM; i += 256) {
        int k = i >> 6, nn = i & 63;
        W2T[nn * 72 + k] = isbf ? ((const unsigned short*)W2)[i] : f2bf(((const float*)W2)[i]);
    }
    if (tid < 64) bs[tid] = loadf(b1, tid, isbf);
    __syncthreads();
    int lane = tid & 63;
    int lane16 = lane & 15, quad = lane >> 4;
    bf16x8 bfrag[4][2];
#pragma unroll
    for (int ct = 0; ct < 4; ++ct)
#pragma unroll
        for (int kc = 0; kc < 2; ++kc)
            bfrag[ct][kc] = *(const bf16x8*)&W2T[(ct * 16 + lane16) * 72 + kc * 32 + quad * 8];
    float bv[2][8];
#pragma unroll
    for (int kc = 0; kc < 2; ++kc)
#pragma unroll
        for (int j = 0; j < 8; ++j) bv[kc][j] = bs[kc * 32 + quad * 8 + j];
    int wid = (blockIdx.x * 256 + tid) >> 6;
    int nw = (gridDim.x * 256) >> 6;
    for (int t = wid; t < NTILES; t += nw) {
        int row0 = t * 16;
        const float* ir = in + (size_t)(row0 + lane16) * HID_DIM;
        bf16x8 afrag[2];
#pragma unroll
        for (int kc = 0; kc < 2; ++kc) {
            f32x4 p0 = *(const f32x4*)(ir + kc * 32 + quad * 8);
            f32x4 p1 = *(const f32x4*)(ir + kc * 32 + quad * 8 + 4);
            bf16x8 a;
#pragma unroll
            for (int j = 0; j < 4; ++j) {
                a[j]     = (short)f2bf(fmaxf(p0[j] + bv[kc][j], 0.0f));
                a[4 + j] = (short)f2bf(fmaxf(p1[j] + bv[kc][4 + j], 0.0f));
            }
            afrag[kc] = a;
        }
        f32x4 acc[4] = {};
#pragma unroll
        for (int kc = 0; kc < 2; ++kc)
#pragma unroll
            for (int ct = 0; ct < 4; ++ct)
                acc[ct] = __builtin_amdgcn_mfma_f32_16x16x32_bf16(afrag[kc], bfrag[ct][kc], acc[ct], 0, 0, 0);
#pragma unroll
        for (int ct = 0; ct < 4; ++ct)
#pragma unroll
            for (int r = 0; r < 4; ++r)
                out[(size_t)(row0 + quad * 4 + r) * EMB_DIM + ct * 16 + lane16] = f2bf(acc[ct][r]);
    }
}

// ---- MFMA head: logits[N,40] = (in[N,64]+b2) @ Wl[64,40] + bl ; log_softmax ----
__global__ __launch_bounds__(256) void k_final(const float* __restrict__ in,
                                               const void* __restrict__ b2,
                                               const void* __restrict__ Wl,
                                               const void* __restrict__ bl,
                                               void* __restrict__ out,
                                               const int* __restrict__ flags, int n) {
    __shared__ unsigned short WlT[48 * 72];  // WlT[n][k], zero for n>=40
    __shared__ float b2s[64];
    int isbf = flags[0];
    int tid = threadIdx.x;
    for (int i = tid; i < 48 * 64; i += 256) {
        int nn = i >> 6, k = i & 63;
        WlT[nn * 72 + k] = (nn < OUT_DIM) ?
            (isbf ? ((const unsigned short*)Wl)[k * OUT_DIM + nn] : f2bf(((const float*)Wl)[k * OUT_DIM + nn]))
            : (unsigned short)0;
    }
    if (tid < 64) b2s[tid] = loadf(b2, tid, isbf);
    __syncthreads();
    int lane = tid & 63;
    int lane16 = lane & 15, quad = lane >> 4;
    bf16x8 bfrag[3][2];
#pragma unroll
    for (int ct = 0; ct < 3; ++ct)
#pragma unroll
        for (int kc = 0; kc < 2; ++kc)
            bfrag[ct][kc] = *(const bf16x8*)&WlT[(ct * 16 + lane16) * 72 + kc * 32 + quad * 8];
    float b2v[2][8];
#pragma unroll
    for (int kc = 0; kc < 2; ++kc)
#pragma unroll
        for (int j = 0; j < 8; ++j) b2v[kc][j] = b2s[kc * 32 + quad * 8 + j];
    float blv[3];
    bool v2 = (lane16 < 8);  // col-tile 2 covers cols 32..47; valid cols <40
#pragma unroll
    for (int ct = 0; ct < 3; ++ct) {
        int col = ct * 16 + lane16;
        blv[ct] = (col < OUT_DIM) ? loadf(bl, col, isbf) : 0.0f;
    }
    int wid = (blockIdx.x * 256 + tid) >> 6;
    int nw = (gridDim.x * 256) >> 6;
    for (int t = wid; t < NTILES; t += nw) {
        int row0 = t * 16;
        const float* ir = in + (size_t)(row0 + lane16) * EMB_DIM;
        bf16x8 afrag[2];
#pragma unroll
        for (int kc = 0; kc < 2; ++kc) {
            f32x4 p0 = *(const f32x4*)(ir + kc * 32 + quad * 8);
            f32x4 p1 = *(const f32x4*)(ir + kc * 32 + quad * 8 + 4);
            bf16x8 a;
#pragma unroll
            for (int j = 0; j < 4; ++j) {
                a[j]     = (short)f2bf(p0[j] + b2v[kc][j]);
                a[4 + j] = (short)f2bf(p1[j] + b2v[kc][4 + j]);
            }
            afrag[kc] = a;
        }
        f32x4 acc[3] = {};
#pragma unroll
        for (int kc = 0; kc < 2; ++kc)
#pragma unroll
            for (int ct = 0; ct < 3; ++ct)
                acc[ct] = __builtin_amdgcn_mfma_f32_16x16x32_bf16(afrag[kc], bfrag[ct][kc], acc[ct], 0, 0, 0);
#pragma unroll
        for (int r = 0; r < 4; ++r) {
            float l0 = acc[0][r] + blv[0];
            float l1 = acc[1][r] + blv[1];
            float l2 = v2 ? (acc[2][r] + blv[2]) : -INFINITY;
            float mx = fmaxf(fmaxf(l0, l1), l2);
#pragma unroll
            for (int s = 1; s < 16; s <<= 1) mx = fmaxf(mx, __shfl_xor(mx, s));
            float sm = expf(l0 - mx) + expf(l1 - mx) + (v2 ? expf(l2 - mx) : 0.0f);
#pragma unroll
            for (int s = 1; s < 16; s <<= 1) sm += __shfl_xor(sm, s);
            float ls = mx + logf(sm);
            int row = row0 + quad * 4 + r;
            size_t o = (size_t)row * OUT_DIM;
            if (isbf) {
                __hip_bfloat16* ob = (__hip_bfloat16*)out;
                ob[o + lane16] = __float2bfloat16(l0 - ls);
                ob[o + 16 + lane16] = __float2bfloat16(l1 - ls);
                if (v2) ob[o + 32 + lane16] = __float2bfloat16(l2 - ls);
            } else {
                float* of = (float*)out;
                of[o + lane16] = l0 - ls;
                of[o + 16 + lane16] = l1 - ls;
                if (v2) of[o + 32 + lane16] = l2 - ls;
            }
        }
    }
}

extern "C" void kernel_launch(void* const* d_in, const int* in_sizes, int n_in,
                              void* d_out, int out_size, void* d_ws, size_t ws_size,
                              hipStream_t stream) {
    const void* x  = d_in[0];
    const void* ei = d_in[1];
    const void* W1 = d_in[2];
    const void* b1 = d_in[3];
    const void* W2 = d_in[4];
    const void* b2 = d_in[5];
    const void* Wl = d_in[6];
    const void* bl = d_in[7];

    float* ws = (float*)d_ws;
    int*   flags     = (int*)ws;                           // [0..63]
    float* dinv      = ws + 64;                            // N floats
    int*   cnt       = (int*)(ws + 100096);                // N ints
    int*   cur       = (int*)(ws + 200128);                // N ints
    int*   blocksums = (int*)(ws + 300160);                // 128 ints
    int*   csr_src   = (int*)(ws + 300416);                // E ints
    unsigned short* bufA = (unsigned short*)(ws + 1900544);// N*64 bf16
    float* bufB      = ws + 5100544;                       // N*64 floats

    const int nblk_node = (N_NODES + 255) / 256;   // 391
    const int nblk_row  = N_NODES / 4;             // 25000 (aggregate)
    const int nblk_scan = (N_NODES + 1023) / 1024; // 98
    const int nblk_mfma = 640;

    k_detect<<<1, 64, 0, stream>>>((const unsigned int*)x, (const unsigned int*)ei, flags);

    // CSR build + dinv
    k_zero<<<nblk_node, 256, 0, stream>>>(cnt, N_NODES);
    k_count<<<2048, 256, 0, stream>>>(ei, cnt, flags, N_EDGES);
    k_dinv<<<nblk_node, 256, 0, stream>>>(cnt, dinv, N_NODES);
    k_scan_a<<<nblk_scan, 256, 0, stream>>>(cnt, blocksums, N_NODES);
    k_scan_b<<<1, 128, 0, stream>>>(blocksums, nblk_scan);
    k_scan_c<<<nblk_scan, 256, 0, stream>>>(cnt, blocksums, cur, N_NODES);
    k_fill<<<2048, 256, 0, stream>>>(ei, cur, csr_src, flags, N_EDGES);

    // layer 1
    k_gemm1<<<nblk_mfma, 256, 0, stream>>>(x, W1, bufA, flags, N_NODES);
    k_aggregate<<<nblk_row, 256, 0, stream>>>(bufA, dinv, cur, csr_src, bufB, N_NODES);

    // layer 2
    k_gemm2<<<nblk_mfma, 256, 0, stream>>>(bufB, W2, b1, bufA, flags, N_NODES);
    k_aggregate<<<nblk_row, 256, 0, stream>>>(bufA, dinv, cur, csr_src, bufB, N_NODES);

    // head
    k_final<<<nblk_mfma, 256, 0, stream>>>(bufB, b2, Wl, bl, d_out, flags, N_NODES);
}

// Round 5
// 478.788 us; speedup vs baseline: 2.8251x; 1.1127x over previous
//
#include <hip/hip_runtime.h>
#include <hip/hip_bf16.h>

#define N_NODES 100000
#define N_EDGES 1600000
#define IN_DIM 128
#define HID_DIM 64
#define EMB_DIM 64
#define OUT_DIM 40
#define NTILES 6250   // N_NODES / 16
#define NB 391        // dst buckets of 256 nodes
#define DEPTH 16
#define FTHRESH 12

typedef __attribute__((ext_vector_type(8))) short bf16x8;
typedef __attribute__((ext_vector_type(4))) float f32x4;

__device__ __forceinline__ float bf2f(unsigned short u) {
    unsigned int v = ((unsigned int)u) << 16;
    float f;
    __builtin_memcpy(&f, &v, 4);
    return f;
}
__device__ __forceinline__ unsigned short f2bf(float f) {
    __hip_bfloat16 b = __float2bfloat16(f);
    unsigned short u;
    __builtin_memcpy(&u, &b, 2);
    return u;
}

// flags[0]: 1 = float tensors are bf16, 0 = fp32
// flags[1]: 1 = edge_index is int64, 0 = int32
__device__ __forceinline__ float loadf(const void* p, size_t i, int isbf) {
    return isbf ? bf2f(((const unsigned short*)p)[i]) : ((const float*)p)[i];
}
__device__ __forceinline__ int loadi(const void* p, size_t i, int is64) {
    return is64 ? (int)(((const long long*)p)[i]) : ((const int*)p)[i];
}

// ---- dtype detection ----
__global__ void k_detect(const unsigned int* __restrict__ xb,
                         const unsigned int* __restrict__ eib,
                         int* __restrict__ flags) {
    int tid = threadIdx.x;
    unsigned int u = xb[tid];
    unsigned int lo_exp = (u >> 7) & 0xFF;
    bool bfplaus = (lo_exp >= 100 && lo_exp <= 140) || ((u & 0xFFFFu) == 0u);
    unsigned long long m1 = __ballot(bfplaus);
    unsigned int hi = eib[2 * tid + 1];
    unsigned long long m2 = __ballot(hi == 0u);
    if (tid == 0) {
        flags[0] = (__popcll(m1) >= 48) ? 1 : 0;
        flags[1] = (m2 == 0xFFFFFFFFFFFFFFFFULL) ? 1 : 0;
    }
}

__global__ void k_zero(int* __restrict__ cnt, int n) {
    int i = blockIdx.x * blockDim.x + threadIdx.x;
    if (i < n) cnt[i] = 0;
}

__global__ void k_count(const void* __restrict__ ei, int* __restrict__ cnt,
                        const int* __restrict__ flags, int E) {
    int is64 = flags[1];
    int i = blockIdx.x * blockDim.x + threadIdx.x;
    int stride = gridDim.x * blockDim.x;
    for (int e = i; e < E; e += stride) {
        int d = loadi(ei, (size_t)N_EDGES + e, is64);
        atomicAdd(&cnt[d], 1);
    }
}

__global__ void k_dinv(const int* __restrict__ cnt, float* __restrict__ dinv, int n) {
    int i = blockIdx.x * blockDim.x + threadIdx.x;
    if (i < n) dinv[i] = rsqrtf(1.0f + (float)cnt[i]);
}

// ---- hierarchical exclusive scan: cnt -> rs (row starts) ----
__global__ __launch_bounds__(256) void k_scan_a(const int* __restrict__ cnt,
                                                int* __restrict__ blocksums, int n) {
    __shared__ int sh[256];
    int t = threadIdx.x, b = blockIdx.x;
    int base = (b * 256 + t) * 4;
    int s = 0;
#pragma unroll
    for (int j = 0; j < 4; ++j) if (base + j < n) s += cnt[base + j];
    sh[t] = s;
    __syncthreads();
    for (int o = 1; o < 256; o <<= 1) {
        int u = (t >= o) ? sh[t - o] : 0;
        __syncthreads();
        sh[t] += u;
        __syncthreads();
    }
    if (t == 255) blocksums[b] = sh[255];
}

__global__ void k_scan_b(int* __restrict__ blocksums, int nb) {
    __shared__ int sh[128];
    int t = threadIdx.x;
    int v = (t < nb) ? blocksums[t] : 0;
    sh[t] = v;
    __syncthreads();
    for (int o = 1; o < 128; o <<= 1) {
        int u = (t >= o) ? sh[t - o] : 0;
        __syncthreads();
        sh[t] += u;
        __syncthreads();
    }
    if (t < nb) blocksums[t] = sh[t] - v;
}

__global__ __launch_bounds__(256) void k_scan_c(const int* __restrict__ cnt,
                                                const int* __restrict__ blocksums,
                                                int* __restrict__ rs, int n) {
    __shared__ int sh[256];
    int t = threadIdx.x, b = blockIdx.x;
    int base = (b * 256 + t) * 4;
    int c[4];
    int s = 0;
#pragma unroll
    for (int j = 0; j < 4; ++j) {
        c[j] = (base + j < n) ? cnt[base + j] : 0;
        s += c[j];
    }
    sh[t] = s;
    __syncthreads();
    for (int o = 1; o < 256; o <<= 1) {
        int u = (t >= o) ? sh[t - o] : 0;
        __syncthreads();
        sh[t] += u;
        __syncthreads();
    }
    int off = blocksums[b] + sh[t] - s;
#pragma unroll
    for (int j = 0; j < 4; ++j) {
        if (base + j < n) rs[base + j] = off;
        off += c[j];
    }
}

// gcur[b] = rs[b*256]; also rs[N] = E
__global__ void k_gcur(int* __restrict__ rs, int* __restrict__ gcur) {
    int b = threadIdx.x + blockIdx.x * blockDim.x;
    if (b < NB) gcur[b] = rs[b * 256];
    if (b == NB) rs[N_NODES] = N_EDGES;
}

// ---- phase 1: LDS-staged multi-split of edges into 391 dst-buckets ----
// binned[p] = (dst_local << 24) | src, bucket regions == CSR bucket ranges
__global__ __launch_bounds__(256) void k_bin(const void* __restrict__ ei,
                                             int* __restrict__ gcur,
                                             unsigned int* __restrict__ binned,
                                             const int* __restrict__ flags, int E) {
    __shared__ unsigned int lbuf[NB * DEPTH];  // ~25 KB
    __shared__ int lcnt[NB];
    int is64 = flags[1];
    int tid = threadIdx.x;
    for (int b = tid; b < NB; b += 256) lcnt[b] = 0;
    __syncthreads();
    int per = (E + gridDim.x - 1) / gridDim.x;
    int e0 = blockIdx.x * per;
    int e1 = min(e0 + per, E);
    for (int base = e0; base < e1; base += 256) {
        int e = base + tid;
        bool act = (e < e1);
        unsigned int val = 0;
        int b = 0, slot = -1;
        if (act) {
            int s = loadi(ei, e, is64);
            int d = loadi(ei, (size_t)N_EDGES + e, is64);
            b = d >> 8;
            val = ((unsigned int)(d & 255) << 24) | (unsigned int)s;
            slot = atomicAdd(&lcnt[b], 1);
            if (slot < DEPTH) lbuf[b * DEPTH + slot] = val;
        }
        __syncthreads();
        if (act && slot >= DEPTH) {  // rare overflow: direct write
            int p = atomicAdd(&gcur[b], 1);
            binned[p] = val;
        }
        for (int b2 = tid; b2 < NB; b2 += 256) {
            int c = lcnt[b2];
            if (c > DEPTH) c = DEPTH;
            if (c >= FTHRESH) {
                int p = atomicAdd(&gcur[b2], c);
                for (int j = 0; j < c; ++j) binned[p + j] = lbuf[b2 * DEPTH + j];
                lcnt[b2] = 0;
            }
        }
        __syncthreads();
    }
    // drain
    for (int b2 = tid; b2 < NB; b2 += 256) {
        int c = lcnt[b2];
        if (c > DEPTH) c = DEPTH;
        if (c > 0) {
            int p = atomicAdd(&gcur[b2], c);
            for (int j = 0; j < c; ++j) binned[p + j] = lbuf[b2 * DEPTH + j];
        }
    }
}

// ---- phase 2: regroup bucket entries by node into exact CSR ----
__global__ __launch_bounds__(256) void k_regroup(const unsigned int* __restrict__ binned,
                                                 const int* __restrict__ rs,
                                                 int* __restrict__ csr_src) {
    __shared__ int lcur[256];
    int b = blockIdx.x, tid = threadIdx.x;
    int n0 = b * 256;
    int nn = min(256, N_NODES - n0);
    if (tid < nn) lcur[tid] = rs[n0 + tid];
    __syncthreads();
    int start = rs[n0];
    int end = rs[n0 + nn];
    for (int i = start + tid; i < end; i += 256) {
        unsigned int v = binned[i];
        int dl = v >> 24;
        int s = v & 0xFFFFFF;
        int p = atomicAdd(&lcur[dl], 1);
        csr_src[p] = s;
    }
}

// ---- MFMA GEMM1: g[N,64] = bf16( dinv[r] * (x[N,128] @ W1[128,64]) ) ----
__global__ __launch_bounds__(256) void k_gemm1(const void* __restrict__ x,
                                               const void* __restrict__ W1,
                                               const float* __restrict__ dinv,
                                               unsigned short* __restrict__ out,
                                               const int* __restrict__ flags, int n) {
    __shared__ unsigned short W1T[64 * 136];
    int isbf = flags[0];
    int tid = threadIdx.x;
    for (int i = tid; i < IN_DIM * HID_DIM; i += 256) {
        int k = i >> 6, nn = i & 63;
        W1T[nn * 136 + k] = isbf ? ((const unsigned short*)W1)[i] : f2bf(((const float*)W1)[i]);
    }
    __syncthreads();
    int lane = tid & 63;
    int lane16 = lane & 15, quad = lane >> 4;
    bf16x8 bfrag[4][4];
#pragma unroll
    for (int ct = 0; ct < 4; ++ct)
#pragma unroll
        for (int kc = 0; kc < 4; ++kc)
            bfrag[ct][kc] = *(const bf16x8*)&W1T[(ct * 16 + lane16) * 136 + kc * 32 + quad * 8];
    int wid = (blockIdx.x * 256 + tid) >> 6;
    int nw = (gridDim.x * 256) >> 6;
    for (int t = wid; t < NTILES; t += nw) {
        int row0 = t * 16;
        bf16x8 afrag[4];
        if (isbf) {
            const unsigned short* xr = (const unsigned short*)x + (size_t)(row0 + lane16) * IN_DIM;
#pragma unroll
            for (int kc = 0; kc < 4; ++kc)
                afrag[kc] = *(const bf16x8*)(xr + kc * 32 + quad * 8);
        } else {
            const float* xr = (const float*)x + (size_t)(row0 + lane16) * IN_DIM;
#pragma unroll
            for (int kc = 0; kc < 4; ++kc) {
                f32x4 p0 = *(const f32x4*)(xr + kc * 32 + quad * 8);
                f32x4 p1 = *(const f32x4*)(xr + kc * 32 + quad * 8 + 4);
                bf16x8 a;
#pragma unroll
                for (int j = 0; j < 4; ++j) {
                    a[j] = (short)f2bf(p0[j]);
                    a[4 + j] = (short)f2bf(p1[j]);
                }
                afrag[kc] = a;
            }
        }
        f32x4 acc[4] = {};
#pragma unroll
        for (int kc = 0; kc < 4; ++kc)
#pragma unroll
            for (int ct = 0; ct < 4; ++ct)
                acc[ct] = __builtin_amdgcn_mfma_f32_16x16x32_bf16(afrag[kc], bfrag[ct][kc], acc[ct], 0, 0, 0);
        float dv[4];
#pragma unroll
        for (int r = 0; r < 4; ++r) dv[r] = dinv[row0 + quad * 4 + r];
#pragma unroll
        for (int ct = 0; ct < 4; ++ct)
#pragma unroll
            for (int r = 0; r < 4; ++r)
                out[(size_t)(row0 + quad * 4 + r) * HID_DIM + ct * 16 + lane16] = f2bf(acc[ct][r] * dv[r]);
    }
}

// gather aggregation: out[d] = dinv[d] * ( g[d] + sum_{s in row d} g[s] ), g pre-scaled
__global__ __launch_bounds__(256) void k_aggregate(const unsigned short* __restrict__ g,
                                                   const float* __restrict__ dinv,
                                                   const int* __restrict__ rs,
                                                   const int* __restrict__ csr_src,
                                                   float* __restrict__ out, int n) {
    int lane = threadIdx.x & 63;
    int half = lane >> 5;
    int col2 = lane & 31;
    int node = blockIdx.x * 4 + (threadIdx.x >> 6);
    if (node >= n) return;
    int start = rs[node];
    int end = rs[node + 1];
    float ax = 0.0f, ay = 0.0f;
    const ushort2* g2 = (const ushort2*)g;
    for (int e = start + half; e < end; e += 2) {
        int s = csr_src[e];
        ushort2 p = g2[(size_t)s * 32 + col2];
        ax += bf2f(p.x);
        ay += bf2f(p.y);
    }
    ax += __shfl_xor(ax, 32);
    ay += __shfl_xor(ay, 32);
    if (half == 0) {
        float dd = dinv[node];
        ushort2 ps = g2[(size_t)node * 32 + col2];
        float2 r;
        r.x = (ax + bf2f(ps.x)) * dd;
        r.y = (ay + bf2f(ps.y)) * dd;
        ((float2*)out)[(size_t)node * 32 + col2] = r;
    }
}

// ---- MFMA GEMM2: g2[N,64] = bf16( dinv[r] * (relu(in[N,64]+b1) @ W2[64,64]) ) ----
__global__ __launch_bounds__(256) void k_gemm2(const float* __restrict__ in,
                                               const void* __restrict__ W2,
                                               const void* __restrict__ b1,
                                               const float* __restrict__ dinv,
                                               unsigned short* __restrict__ out,
                                               const int* __restrict__ flags, int n) {
    __shared__ unsigned short W2T[64 * 72];
    __shared__ float bs[64];
    int isbf = flags[0];
    int tid = threadIdx.x;
    for (int i = tid; i < HID_DIM * EMB_DIM; i += 256) {
        int k = i >> 6, nn = i & 63;
        W2T[nn * 72 + k] = isbf ? ((const unsigned short*)W2)[i] : f2bf(((const float*)W2)[i]);
    }
    if (tid < 64) bs[tid] = loadf(b1, tid, isbf);
    __syncthreads();
    int lane = tid & 63;
    int lane16 = lane & 15, quad = lane >> 4;
    bf16x8 bfrag[4][2];
#pragma unroll
    for (int ct = 0; ct < 4; ++ct)
#pragma unroll
        for (int kc = 0; kc < 2; ++kc)
            bfrag[ct][kc] = *(const bf16x8*)&W2T[(ct * 16 + lane16) * 72 + kc * 32 + quad * 8];
    float bv[2][8];
#pragma unroll
    for (int kc = 0; kc < 2; ++kc)
#pragma unroll
        for (int j = 0; j < 8; ++j) bv[kc][j] = bs[kc * 32 + quad * 8 + j];
    int wid = (blockIdx.x * 256 + tid) >> 6;
    int nw = (gridDim.x * 256) >> 6;
    for (int t = wid; t < NTILES; t += nw) {
        int row0 = t * 16;
        const float* ir = in + (size_t)(row0 + lane16) * HID_DIM;
        bf16x8 afrag[2];
#pragma unroll
        for (int kc = 0; kc < 2; ++kc) {
            f32x4 p0 = *(const f32x4*)(ir + kc * 32 + quad * 8);
            f32x4 p1 = *(const f32x4*)(ir + kc * 32 + quad * 8 + 4);
            bf16x8 a;
#pragma unroll
            for (int j = 0; j < 4; ++j) {
                a[j]     = (short)f2bf(fmaxf(p0[j] + bv[kc][j], 0.0f));
                a[4 + j] = (short)f2bf(fmaxf(p1[j] + bv[kc][4 + j], 0.0f));
            }
            afrag[kc] = a;
        }
        f32x4 acc[4] = {};
#pragma unroll
        for (int kc = 0; kc < 2; ++kc)
#pragma unroll
            for (int ct = 0; ct < 4; ++ct)
                acc[ct] = __builtin_amdgcn_mfma_f32_16x16x32_bf16(afrag[kc], bfrag[ct][kc], acc[ct], 0, 0, 0);
        float dv[4];
#pragma unroll
        for (int r = 0; r < 4; ++r) dv[r] = dinv[row0 + quad * 4 + r];
#pragma unroll
        for (int ct = 0; ct < 4; ++ct)
#pragma unroll
            for (int r = 0; r < 4; ++r)
                out[(size_t)(row0 + quad * 4 + r) * EMB_DIM + ct * 16 + lane16] = f2bf(acc[ct][r] * dv[r]);
    }
}

// ---- MFMA head: logits = (in+b2) @ Wl + bl ; log_softmax ----
__global__ __launch_bounds__(256) void k_final(const float* __restrict__ in,
                                               const void* __restrict__ b2,
                                               const void* __restrict__ Wl,
                                               const void* __restrict__ bl,
                                               void* __restrict__ out,
                                               const int* __restrict__ flags, int n) {
    __shared__ unsigned short WlT[48 * 72];
    __shared__ float b2s[64];
    int isbf = flags[0];
    int tid = threadIdx.x;
    for (int i = tid; i < 48 * 64; i += 256) {
        int nn = i >> 6, k = i & 63;
        WlT[nn * 72 + k] = (nn < OUT_DIM) ?
            (isbf ? ((const unsigned short*)Wl)[k * OUT_DIM + nn] : f2bf(((const float*)Wl)[k * OUT_DIM + nn]))
            : (unsigned short)0;
    }
    if (tid < 64) b2s[tid] = loadf(b2, tid, isbf);
    __syncthreads();
    int lane = tid & 63;
    int lane16 = lane & 15, quad = lane >> 4;
    bf16x8 bfrag[3][2];
#pragma unroll
    for (int ct = 0; ct < 3; ++ct)
#pragma unroll
        for (int kc = 0; kc < 2; ++kc)
            bfrag[ct][kc] = *(const bf16x8*)&WlT[(ct * 16 + lane16) * 72 + kc * 32 + quad * 8];
    float b2v[2][8];
#pragma unroll
    for (int kc = 0; kc < 2; ++kc)
#pragma unroll
        for (int j = 0; j < 8; ++j) b2v[kc][j] = b2s[kc * 32 + quad * 8 + j];
    float blv[3];
    bool v2 = (lane16 < 8);
#pragma unroll
    for (int ct = 0; ct < 3; ++ct) {
        int col = ct * 16 + lane16;
        blv[ct] = (col < OUT_DIM) ? loadf(bl, col, isbf) : 0.0f;
    }
    int wid = (blockIdx.x * 256 + tid) >> 6;
    int nw = (gridDim.x * 256) >> 6;
    for (int t = wid; t < NTILES; t += nw) {
        int row0 = t * 16;
        const float* ir = in + (size_t)(row0 + lane16) * EMB_DIM;
        bf16x8 afrag[2];
#pragma unroll
        for (int kc = 0; kc < 2; ++kc) {
            f32x4 p0 = *(const f32x4*)(ir + kc * 32 + quad * 8);
            f32x4 p1 = *(const f32x4*)(ir + kc * 32 + quad * 8 + 4);
            bf16x8 a;
#pragma unroll
            for (int j = 0; j < 4; ++j) {
                a[j]     = (short)f2bf(p0[j] + b2v[kc][j]);
                a[4 + j] = (short)f2bf(p1[j] + b2v[kc][4 + j]);
            }
            afrag[kc] = a;
        }
        f32x4 acc[3] = {};
#pragma unroll
        for (int kc = 0; kc < 2; ++kc)
#pragma unroll
            for (int ct = 0; ct < 3; ++ct)
                acc[ct] = __builtin_amdgcn_mfma_f32_16x16x32_bf16(afrag[kc], bfrag[ct][kc], acc[ct], 0, 0, 0);
#pragma unroll
        for (int r = 0; r < 4; ++r) {
            float l0 = acc[0][r] + blv[0];
            float l1 = acc[1][r] + blv[1];
            float l2 = v2 ? (acc[2][r] + blv[2]) : -INFINITY;
            float mx = fmaxf(fmaxf(l0, l1), l2);
#pragma unroll
            for (int s = 1; s < 16; s <<= 1) mx = fmaxf(mx, __shfl_xor(mx, s));
            float sm = expf(l0 - mx) + expf(l1 - mx) + (v2 ? expf(l2 - mx) : 0.0f);
#pragma unroll
            for (int s = 1; s < 16; s <<= 1) sm += __shfl_xor(sm, s);
            float ls = mx + logf(sm);
            int row = row0 + quad * 4 + r;
            size_t o = (size_t)row * OUT_DIM;
            if (isbf) {
                __hip_bfloat16* ob = (__hip_bfloat16*)out;
                ob[o + lane16] = __float2bfloat16(l0 - ls);
                ob[o + 16 + lane16] = __float2bfloat16(l1 - ls);
                if (v2) ob[o + 32 + lane16] = __float2bfloat16(l2 - ls);
            } else {
                float* of = (float*)out;
                of[o + lane16] = l0 - ls;
                of[o + 16 + lane16] = l1 - ls;
                if (v2) of[o + 32 + lane16] = l2 - ls;
            }
        }
    }
}

extern "C" void kernel_launch(void* const* d_in, const int* in_sizes, int n_in,
                              void* d_out, int out_size, void* d_ws, size_t ws_size,
                              hipStream_t stream) {
    const void* x  = d_in[0];
    const void* ei = d_in[1];
    const void* W1 = d_in[2];
    const void* b1 = d_in[3];
    const void* W2 = d_in[4];
    const void* b2 = d_in[5];
    const void* Wl = d_in[6];
    const void* bl = d_in[7];

    float* ws = (float*)d_ws;
    int*   flags     = (int*)ws;                            // 64 slots
    float* dinv      = ws + 64;                             // N floats
    int*   cnt       = (int*)(ws + 100096);                 // N ints
    int*   rs        = (int*)(ws + 200128);                 // N+1 ints
    int*   blocksums = (int*)(ws + 300160);                 // 128 ints
    int*   gcur      = (int*)(ws + 300416);                 // NB ints
    int*   csr_src   = (int*)(ws + 300864);                 // E ints
    unsigned short* g = (unsigned short*)(ws + 1900864);    // N*64 bf16
    float* bufB      = ws + 5100864;                        // N*64 floats
    unsigned int* binned = (unsigned int*)bufB;             // E ints, aliases bufB (dead before agg1)

    const int nblk_node = (N_NODES + 255) / 256;   // 391
    const int nblk_row  = N_NODES / 4;             // 25000
    const int nblk_scan = (N_NODES + 1023) / 1024; // 98
    const int nblk_mfma = 640;

    k_detect<<<1, 64, 0, stream>>>((const unsigned int*)x, (const unsigned int*)ei, flags);

    // degree + dinv + row starts
    k_zero<<<nblk_node, 256, 0, stream>>>(cnt, N_NODES);
    k_count<<<2048, 256, 0, stream>>>(ei, cnt, flags, N_EDGES);
    k_dinv<<<nblk_node, 256, 0, stream>>>(cnt, dinv, N_NODES);
    k_scan_a<<<nblk_scan, 256, 0, stream>>>(cnt, blocksums, N_NODES);
    k_scan_b<<<1, 128, 0, stream>>>(blocksums, nblk_scan);
    k_scan_c<<<nblk_scan, 256, 0, stream>>>(cnt, blocksums, rs, N_NODES);
    k_gcur<<<1, 512, 0, stream>>>(rs, gcur);

    // two-phase CSR build
    k_bin<<<256, 256, 0, stream>>>(ei, gcur, binned, flags, N_EDGES);
    k_regroup<<<NB, 256, 0, stream>>>(binned, rs, csr_src);

    // layer 1
    k_gemm1<<<nblk_mfma, 256, 0, stream>>>(x, W1, dinv, g, flags, N_NODES);
    k_aggregate<<<nblk_row, 256, 0, stream>>>(g, dinv, rs, csr_src, bufB, N_NODES);

    // layer 2
    k_gemm2<<<nblk_mfma, 256, 0, stream>>>(bufB, W2, b1, dinv, g, flags, N_NODES);
    k_aggregate<<<nblk_row, 256, 0, stream>>>(g, dinv, rs, csr_src, bufB, N_NODES);

    // head
    k_final<<<nblk_mfma, 256, 0, stream>>>(bufB, b2, Wl, bl, d_out, flags, N_NODES);
}

// Round 7
// 296.351 us; speedup vs baseline: 4.5643x; 1.6156x over previous
//
#include <hip/hip_runtime.h>
#include <hip/hip_bf16.h>

#define N_NODES 100000
#define N_EDGES 1600000
#define IN_DIM 128
#define HID_DIM 64
#define EMB_DIM 64
#define OUT_DIM 40
#define NTILES 6250   // N_NODES / 16
#define NB 391        // dst buckets of 256 nodes
#define DEPTH 16
#define FTHRESH 12
#define CAP 5120      // per-bucket capacity (mean 4092, 16 sigma headroom)

typedef __attribute__((ext_vector_type(8))) short bf16x8;
typedef __attribute__((ext_vector_type(4))) float f32x4;

__device__ __forceinline__ float bf2f(unsigned short u) {
    unsigned int v = ((unsigned int)u) << 16;
    float f;
    __builtin_memcpy(&f, &v, 4);
    return f;
}
__device__ __forceinline__ unsigned short f2bf(float f) {
    __hip_bfloat16 b = __float2bfloat16(f);
    unsigned short u;
    __builtin_memcpy(&u, &b, 2);
    return u;
}

// flags[0]: 1 = float tensors are bf16, 0 = fp32
// flags[1]: 1 = edge_index is int64, 0 = int32
__device__ __forceinline__ float loadf(const void* p, size_t i, int isbf) {
    return isbf ? bf2f(((const unsigned short*)p)[i]) : ((const float*)p)[i];
}
__device__ __forceinline__ int loadi(const void* p, size_t i, int is64) {
    return is64 ? (int)(((const long long*)p)[i]) : ((const int*)p)[i];
}

// ---- dtype detection ----
__global__ void k_detect(const unsigned int* __restrict__ xb,
                         const unsigned int* __restrict__ eib,
                         int* __restrict__ flags) {
    int tid = threadIdx.x;
    unsigned int u = xb[tid];
    unsigned int lo_exp = (u >> 7) & 0xFF;
    bool bfplaus = (lo_exp >= 100 && lo_exp <= 140) || ((u & 0xFFFFu) == 0u);
    unsigned long long m1 = __ballot(bfplaus);
    unsigned int hi = eib[2 * tid + 1];
    unsigned long long m2 = __ballot(hi == 0u);
    if (tid == 0) {
        flags[0] = (__popcll(m1) >= 48) ? 1 : 0;
        flags[1] = (m2 == 0xFFFFFFFFFFFFFFFFULL) ? 1 : 0;
    }
}

// gcur[b] = b*CAP
__global__ void k_ginit(int* __restrict__ gcur) {
    int b = blockIdx.x * blockDim.x + threadIdx.x;
    if (b < NB) gcur[b] = b * CAP;
}

// ---- phase 1: LDS-staged multi-split of edges into fixed-capacity dst-buckets ----
// binned[p] = (dst_local << 24) | src
__global__ __launch_bounds__(256) void k_bin(const void* __restrict__ ei,
                                             int* __restrict__ gcur,
                                             unsigned int* __restrict__ binned,
                                             const int* __restrict__ flags, int E) {
    __shared__ unsigned int lbuf[NB * DEPTH];  // ~25 KB
    __shared__ int lcnt[NB];
    int is64 = flags[1];
    int tid = threadIdx.x;
    for (int b = tid; b < NB; b += 256) lcnt[b] = 0;
    __syncthreads();
    int per = (E + gridDim.x - 1) / gridDim.x;
    int e0 = blockIdx.x * per;
    int e1 = min(e0 + per, E);
    for (int base = e0; base < e1; base += 256) {
        int e = base + tid;
        bool act = (e < e1);
        unsigned int val = 0;
        int b = 0, slot = -1;
        if (act) {
            int s = loadi(ei, e, is64);
            int d = loadi(ei, (size_t)N_EDGES + e, is64);
            b = d >> 8;
            val = ((unsigned int)(d & 255) << 24) | (unsigned int)s;
            slot = atomicAdd(&lcnt[b], 1);
            if (slot < DEPTH) lbuf[b * DEPTH + slot] = val;
        }
        __syncthreads();
        if (act && slot >= DEPTH) {  // rare overflow: direct write
            int p = atomicAdd(&gcur[b], 1);
            if (p < (b + 1) * CAP) binned[p] = val;
        }
        for (int b2 = tid; b2 < NB; b2 += 256) {
            int c = lcnt[b2];
            if (c > DEPTH) c = DEPTH;
            if (c >= FTHRESH) {
                int p = atomicAdd(&gcur[b2], c);
                int lim = (b2 + 1) * CAP;
                for (int j = 0; j < c; ++j) if (p + j < lim) binned[p + j] = lbuf[b2 * DEPTH + j];
                lcnt[b2] = 0;
            }
        }
        __syncthreads();
    }
    // drain
    for (int b2 = tid; b2 < NB; b2 += 256) {
        int c = lcnt[b2];
        if (c > DEPTH) c = DEPTH;
        if (c > 0) {
            int p = atomicAdd(&gcur[b2], c);
            int lim = (b2 + 1) * CAP;
            for (int j = 0; j < c; ++j) if (p + j < lim) binned[p + j] = lbuf[b2 * DEPTH + j];
        }
    }
}

// ---- scan bucket totals -> btot (exclusive), rs[N]=E ----
__global__ void k_bscan(const int* __restrict__ gcur, int* __restrict__ btot,
                        int* __restrict__ rs) {
    __shared__ int sh[512];
    int t = threadIdx.x;
    int v = 0;
    if (t < NB) {
        v = gcur[t] - t * CAP;
        if (v > CAP) v = CAP;
    }
    sh[t] = v;
    __syncthreads();
    for (int o = 1; o < 512; o <<= 1) {
        int u = (t >= o) ? sh[t - o] : 0;
        __syncthreads();
        sh[t] += u;
        __syncthreads();
    }
    if (t < NB) btot[t] = sh[t] - v;
    if (t == NB) rs[N_NODES] = N_EDGES;
}

// ---- phase 2: per bucket, count per node, scan, write rs/dinv + exact CSR ----
__global__ __launch_bounds__(256) void k_regroup(const unsigned int* __restrict__ binned,
                                                 const int* __restrict__ btot,
                                                 const int* __restrict__ gcur,
                                                 int* __restrict__ csr_src,
                                                 int* __restrict__ rs,
                                                 float* __restrict__ dinv) {
    __shared__ int lcnt[256];
    __shared__ int lofs[256];
    int b = blockIdx.x, tid = threadIdx.x;
    int n0 = b * 256;
    int nn = min(256, N_NODES - n0);
    lcnt[tid] = 0;
    __syncthreads();
    int src0 = b * CAP;
    int m = gcur[b] - src0;
    if (m > CAP) m = CAP;
    for (int i = tid; i < m; i += 256) {
        atomicAdd(&lcnt[binned[src0 + i] >> 24], 1);
    }
    __syncthreads();
    int c = lcnt[tid];
    lofs[tid] = c;
    __syncthreads();
    for (int o = 1; o < 256; o <<= 1) {
        int u = (tid >= o) ? lofs[tid - o] : 0;
        __syncthreads();
        lofs[tid] += u;
        __syncthreads();
    }
    int base = btot[b];
    int mystart = base + lofs[tid] - c;
    if (tid < nn) {
        rs[n0 + tid] = mystart;
        dinv[n0 + tid] = rsqrtf(1.0f + (float)c);
    }
    __syncthreads();
    lofs[tid] = mystart;  // reuse as cursors
    __syncthreads();
    for (int i = tid; i < m; i += 256) {
        unsigned int v = binned[src0 + i];
        int p = atomicAdd(&lofs[v >> 24], 1);
        csr_src[p] = v & 0xFFFFFF;
    }
}

// ---- MFMA GEMM1: g[N,64] = bf16( dinv[r] * (x[N,128] @ W1[128,64]) ) ----
__global__ __launch_bounds__(256) void k_gemm1(const void* __restrict__ x,
                                               const void* __restrict__ W1,
                                               const float* __restrict__ dinv,
                                               unsigned short* __restrict__ out,
                                               const int* __restrict__ flags, int n) {
    __shared__ unsigned short W1T[64 * 136];
    int isbf = flags[0];
    int tid = threadIdx.x;
    for (int i = tid; i < IN_DIM * HID_DIM; i += 256) {
        int k = i >> 6, nn = i & 63;
        W1T[nn * 136 + k] = isbf ? ((const unsigned short*)W1)[i] : f2bf(((const float*)W1)[i]);
    }
    __syncthreads();
    int lane = tid & 63;
    int lane16 = lane & 15, quad = lane >> 4;
    bf16x8 bfrag[4][4];
#pragma unroll
    for (int ct = 0; ct < 4; ++ct)
#pragma unroll
        for (int kc = 0; kc < 4; ++kc)
            bfrag[ct][kc] = *(const bf16x8*)&W1T[(ct * 16 + lane16) * 136 + kc * 32 + quad * 8];
    int wid = (blockIdx.x * 256 + tid) >> 6;
    int nw = (gridDim.x * 256) >> 6;
    for (int t = wid; t < NTILES; t += nw) {
        int row0 = t * 16;
        bf16x8 afrag[4];
        if (isbf) {
            const unsigned short* xr = (const unsigned short*)x + (size_t)(row0 + lane16) * IN_DIM;
#pragma unroll
            for (int kc = 0; kc < 4; ++kc)
                afrag[kc] = *(const bf16x8*)(xr + kc * 32 + quad * 8);
        } else {
            const float* xr = (const float*)x + (size_t)(row0 + lane16) * IN_DIM;
#pragma unroll
            for (int kc = 0; kc < 4; ++kc) {
                f32x4 p0 = *(const f32x4*)(xr + kc * 32 + quad * 8);
                f32x4 p1 = *(const f32x4*)(xr + kc * 32 + quad * 8 + 4);
                bf16x8 a;
#pragma unroll
                for (int j = 0; j < 4; ++j) {
                    a[j] = (short)f2bf(p0[j]);
                    a[4 + j] = (short)f2bf(p1[j]);
                }
                afrag[kc] = a;
            }
        }
        f32x4 acc[4] = {};
#pragma unroll
        for (int kc = 0; kc < 4; ++kc)
#pragma unroll
            for (int ct = 0; ct < 4; ++ct)
                acc[ct] = __builtin_amdgcn_mfma_f32_16x16x32_bf16(afrag[kc], bfrag[ct][kc], acc[ct], 0, 0, 0);
        float dv[4];
#pragma unroll
        for (int r = 0; r < 4; ++r) dv[r] = dinv[row0 + quad * 4 + r];
#pragma unroll
        for (int ct = 0; ct < 4; ++ct)
#pragma unroll
            for (int r = 0; r < 4; ++r)
                out[(size_t)(row0 + quad * 4 + r) * HID_DIM + ct * 16 + lane16] = f2bf(acc[ct][r] * dv[r]);
    }
}

// gather aggregation with register-prefetched indices + 4 independent gathers in flight
// out[d] = dinv[d] * ( g[d] + sum_{s in row d} g[s] ), g pre-scaled by dinv[s]
__global__ __launch_bounds__(256) void k_aggregate(const unsigned short* __restrict__ g,
                                                   const float* __restrict__ dinv,
                                                   const int* __restrict__ rs,
                                                   const int* __restrict__ csr_src,
                                                   float* __restrict__ out, int n) {
    int lane = threadIdx.x & 63;
    int half = lane >> 5;
    int col2 = lane & 31;
    int node = blockIdx.x * 4 + (threadIdx.x >> 6);
    if (node >= n) return;
    int start = rs[node];
    int m_all = rs[node + 1] - start;
    const ushort2* g2 = (const ushort2*)g;
    float ax = 0.0f, ay = 0.0f;
    for (int base = 0; base < m_all; base += 64) {
        int m = min(64, m_all - base);
        int idx = (lane < m) ? csr_src[start + base + lane] : node;  // pad with valid addr
        int nIt = (m + 7) >> 3;
        for (int it = 0; it < nIt; ++it) {
            int j0 = it * 8 + half * 4;
            int i0 = __shfl(idx, j0 + 0);
            int i1 = __shfl(idx, j0 + 1);
            int i2 = __shfl(idx, j0 + 2);
            int i3 = __shfl(idx, j0 + 3);
            ushort2 p0 = g2[(size_t)i0 * 32 + col2];
            ushort2 p1 = g2[(size_t)i1 * 32 + col2];
            ushort2 p2 = g2[(size_t)i2 * 32 + col2];
            ushort2 p3 = g2[(size_t)i3 * 32 + col2];
            if (j0 + 0 < m) { ax += bf2f(p0.x); ay += bf2f(p0.y); }
            if (j0 + 1 < m) { ax += bf2f(p1.x); ay += bf2f(p1.y); }
            if (j0 + 2 < m) { ax += bf2f(p2.x); ay += bf2f(p2.y); }
            if (j0 + 3 < m) { ax += bf2f(p3.x); ay += bf2f(p3.y); }
        }
    }
    ax += __shfl_xor(ax, 32);
    ay += __shfl_xor(ay, 32);
    if (half == 0) {
        float dd = dinv[node];
        ushort2 ps = g2[(size_t)node * 32 + col2];
        float2 r;
        r.x = (ax + bf2f(ps.x)) * dd;
        r.y = (ay + bf2f(ps.y)) * dd;
        ((float2*)out)[(size_t)node * 32 + col2] = r;
    }
}

// ---- MFMA GEMM2: g2[N,64] = bf16( dinv[r] * (relu(in[N,64]+b1) @ W2[64,64]) ) ----
__global__ __launch_bounds__(256) void k_gemm2(const float* __restrict__ in,
                                               const void* __restrict__ W2,
                                               const void* __restrict__ b1,
                                               const float* __restrict__ dinv,
                                               unsigned short* __restrict__ out,
                                               const int* __restrict__ flags, int n) {
    __shared__ unsigned short W2T[64 * 72];
    __shared__ float bs[64];
    int isbf = flags[0];
    int tid = threadIdx.x;
    for (int i = tid; i < HID_DIM * EMB_DIM; i += 256) {
        int k = i >> 6, nn = i & 63;
        W2T[nn * 72 + k] = isbf ? ((const unsigned short*)W2)[i] : f2bf(((const float*)W2)[i]);
    }
    if (tid < 64) bs[tid] = loadf(b1, tid, isbf);
    __syncthreads();
    int lane = tid & 63;
    int lane16 = lane & 15, quad = lane >> 4;
    bf16x8 bfrag[4][2];
#pragma unroll
    for (int ct = 0; ct < 4; ++ct)
#pragma unroll
        for (int kc = 0; kc < 2; ++kc)
            bfrag[ct][kc] = *(const bf16x8*)&W2T[(ct * 16 + lane16) * 72 + kc * 32 + quad * 8];
    float bv[2][8];
#pragma unroll
    for (int kc = 0; kc < 2; ++kc)
#pragma unroll
        for (int j = 0; j < 8; ++j) bv[kc][j] = bs[kc * 32 + quad * 8 + j];
    int wid = (blockIdx.x * 256 + tid) >> 6;
    int nw = (gridDim.x * 256) >> 6;
    for (int t = wid; t < NTILES; t += nw) {
        int row0 = t * 16;
        const float* ir = in + (size_t)(row0 + lane16) * HID_DIM;
        bf16x8 afrag[2];
#pragma unroll
        for (int kc = 0; kc < 2; ++kc) {
            f32x4 p0 = *(const f32x4*)(ir + kc * 32 + quad * 8);
            f32x4 p1 = *(const f32x4*)(ir + kc * 32 + quad * 8 + 4);
            bf16x8 a;
#pragma unroll
            for (int j = 0; j < 4; ++j) {
                a[j]     = (short)f2bf(fmaxf(p0[j] + bv[kc][j], 0.0f));
                a[4 + j] = (short)f2bf(fmaxf(p1[j] + bv[kc][4 + j], 0.0f));
            }
            afrag[kc] = a;
        }
        f32x4 acc[4] = {};
#pragma unroll
        for (int kc = 0; kc < 2; ++kc)
#pragma unroll
            for (int ct = 0; ct < 4; ++ct)
                acc[ct] = __builtin_amdgcn_mfma_f32_16x16x32_bf16(afrag[kc], bfrag[ct][kc], acc[ct], 0, 0, 0);
        float dv[4];
#pragma unroll
        for (int r = 0; r < 4; ++r) dv[r] = dinv[row0 + quad * 4 + r];
#pragma unroll
        for (int ct = 0; ct < 4; ++ct)
#pragma unroll
            for (int r = 0; r < 4; ++r)
                out[(size_t)(row0 + quad * 4 + r) * EMB_DIM + ct * 16 + lane16] = f2bf(acc[ct][r] * dv[r]);
    }
}

// ---- MFMA head: logits = (in+b2) @ Wl + bl ; log_softmax ----
__global__ __launch_bounds__(256) void k_final(const float* __restrict__ in,
                                               const void* __restrict__ b2,
                                               const void* __restrict__ Wl,
                                               const void* __restrict__ bl,
                                               void* __restrict__ out,
                                               const int* __restrict__ flags, int n) {
    __shared__ unsigned short WlT[48 * 72];
    __shared__ float b2s[64];
    int isbf = flags[0];
    int tid = threadIdx.x;
    for (int i = tid; i < 48 * 64; i += 256) {
        int nn = i >> 6, k = i & 63;
        WlT[nn * 72 + k] = (nn < OUT_DIM) ?
            (isbf ? ((const unsigned short*)Wl)[k * OUT_DIM + nn] : f2bf(((const float*)Wl)[k * OUT_DIM + nn]))
            : (unsigned short)0;
    }
    if (tid < 64) b2s[tid] = loadf(b2, tid, isbf);
    __syncthreads();
    int lane = tid & 63;
    int lane16 = lane & 15, quad = lane >> 4;
    bf16x8 bfrag[3][2];
#pragma unroll
    for (int ct = 0; ct < 3; ++ct)
#pragma unroll
        for (int kc = 0; kc < 2; ++kc)
            bfrag[ct][kc] = *(const bf16x8*)&WlT[(ct * 16 + lane16) * 72 + kc * 32 + quad * 8];
    float b2v[2][8];
#pragma unroll
    for (int kc = 0; kc < 2; ++kc)
#pragma unroll
        for (int j = 0; j < 8; ++j) b2v[kc][j] = b2s[kc * 32 + quad * 8 + j];
    float blv[3];
    bool v2 = (lane16 < 8);
#pragma unroll
    for (int ct = 0; ct < 3; ++ct) {
        int col = ct * 16 + lane16;
        blv[ct] = (col < OUT_DIM) ? loadf(bl, col, isbf) : 0.0f;
    }
    int wid = (blockIdx.x * 256 + tid) >> 6;
    int nw = (gridDim.x * 256) >> 6;
    for (int t = wid; t < NTILES; t += nw) {
        int row0 = t * 16;
        const float* ir = in + (size_t)(row0 + lane16) * EMB_DIM;
        bf16x8 afrag[2];
#pragma unroll
        for (int kc = 0; kc < 2; ++kc) {
            f32x4 p0 = *(const f32x4*)(ir + kc * 32 + quad * 8);
            f32x4 p1 = *(const f32x4*)(ir + kc * 32 + quad * 8 + 4);
            bf16x8 a;
#pragma unroll
            for (int j = 0; j < 4; ++j) {
                a[j]     = (short)f2bf(p0[j] + b2v[kc][j]);
                a[4 + j] = (short)f2bf(p1[j] + b2v[kc][4 + j]);
            }
            afrag[kc] = a;
        }
        f32x4 acc[3] = {};
#pragma unroll
        for (int kc = 0; kc < 2; ++kc)
#pragma unroll
            for (int ct = 0; ct < 3; ++ct)
                acc[ct] = __builtin_amdgcn_mfma_f32_16x16x32_bf16(afrag[kc], bfrag[ct][kc], acc[ct], 0, 0, 0);
#pragma unroll
        for (int r = 0; r < 4; ++r) {
            float l0 = acc[0][r] + blv[0];
            float l1 = acc[1][r] + blv[1];
            float l2 = v2 ? (acc[2][r] + blv[2]) : -INFINITY;
            float mx = fmaxf(fmaxf(l0, l1), l2);
#pragma unroll
            for (int s = 1; s < 16; s <<= 1) mx = fmaxf(mx, __shfl_xor(mx, s));
            float sm = expf(l0 - mx) + expf(l1 - mx) + (v2 ? expf(l2 - mx) : 0.0f);
#pragma unroll
            for (int s = 1; s < 16; s <<= 1) sm += __shfl_xor(sm, s);
            float ls = mx + logf(sm);
            int row = row0 + quad * 4 + r;
            size_t o = (size_t)row * OUT_DIM;
            if (isbf) {
                __hip_bfloat16* ob = (__hip_bfloat16*)out;
                ob[o + lane16] = __float2bfloat16(l0 - ls);
                ob[o + 16 + lane16] = __float2bfloat16(l1 - ls);
                if (v2) ob[o + 32 + lane16] = __float2bfloat16(l2 - ls);
            } else {
                float* of = (float*)out;
                of[o + lane16] = l0 - ls;
                of[o + 16 + lane16] = l1 - ls;
                if (v2) of[o + 32 + lane16] = l2 - ls;
            }
        }
    }
}

extern "C" void kernel_launch(void* const* d_in, const int* in_sizes, int n_in,
                              void* d_out, int out_size, void* d_ws, size_t ws_size,
                              hipStream_t stream) {
    const void* x  = d_in[0];
    const void* ei = d_in[1];
    const void* W1 = d_in[2];
    const void* b1 = d_in[3];
    const void* W2 = d_in[4];
    const void* b2 = d_in[5];
    const void* Wl = d_in[6];
    const void* bl = d_in[7];

    float* ws = (float*)d_ws;
    // layout (float-slot offsets) — g is N*64 bf16 = 3,200,000 FLOAT slots (R6 bug: undersized)
    int*   flags   = (int*)ws;                             // [0,64)
    float* dinv    = ws + 64;                              // [64, 100064) -> pad to 100096
    int*   rs      = (int*)(ws + 100096);                  // N+1 ints -> ends 200097, pad to 200224
    int*   btot    = (int*)(ws + 200224);                  // 512 slots
    int*   gcur    = (int*)(ws + 200736);                  // 512 slots
    int*   csr_src = (int*)(ws + 201248);                  // E ints -> ends 1801248
    unsigned short* g = (unsigned short*)(ws + 1801248);   // N*64 bf16 -> ends 5001248
    float* bufB    = ws + 5001248;                         // N*64 floats -> ends 11401248 (45.6 MB)
    unsigned int* binned = (unsigned int*)bufB;            // NB*CAP=2,001,920 ints (8MB), aliases bufB

    k_detect<<<1, 64, 0, stream>>>((const unsigned int*)x, (const unsigned int*)ei, flags);

    // CSR build: bin -> bucket scan -> regroup (counts+scan+fill+rs+dinv)
    k_ginit<<<2, 256, 0, stream>>>(gcur);
    k_bin<<<512, 256, 0, stream>>>(ei, gcur, binned, flags, N_EDGES);
    k_bscan<<<1, 512, 0, stream>>>(gcur, btot, rs);
    k_regroup<<<NB, 256, 0, stream>>>(binned, btot, gcur, csr_src, rs, dinv);

    // layer 1
    k_gemm1<<<640, 256, 0, stream>>>(x, W1, dinv, g, flags, N_NODES);
    k_aggregate<<<25000, 256, 0, stream>>>(g, dinv, rs, csr_src, bufB, N_NODES);

    // layer 2
    k_gemm2<<<640, 256, 0, stream>>>(bufB, W2, b1, dinv, g, flags, N_NODES);
    k_aggregate<<<25000, 256, 0, stream>>>(g, dinv, rs, csr_src, bufB, N_NODES);

    // head
    k_final<<<640, 256, 0, stream>>>(bufB, b2, Wl, bl, d_out, flags, N_NODES);
}